// Round 11
// baseline (914.481 us; speedup 1.0000x reference)
//
#include <hip/hip_runtime.h>
#include <hip/hip_bf16.h>

#define HDIM 2048
#define IDIM 1024
#define NEXP 16
#define TTOK 4096   // B*S tokens
#define KTOP 2

typedef __attribute__((ext_vector_type(4))) float f32x4;
typedef __attribute__((ext_vector_type(8))) short bf16x8;
typedef __attribute__((ext_vector_type(4))) unsigned short u16x4;

__device__ __forceinline__ unsigned short f2b(float f) {
  __hip_bfloat16 h = __float2bfloat16(f);
  return *reinterpret_cast<unsigned short*>(&h);
}

// phase-boundary primitives: counted vmcnt (T4) — never drain to 0 mid-loop.
#define WAIT_VM0()   { asm volatile("s_waitcnt vmcnt(0)" ::: "memory"); __builtin_amdgcn_sched_barrier(0); }
#define WAIT_VM12()  { asm volatile("s_waitcnt vmcnt(12)" ::: "memory"); __builtin_amdgcn_sched_barrier(0); }
#define WAIT_LGKM0() { asm volatile("s_waitcnt lgkmcnt(0)" ::: "memory"); __builtin_amdgcn_sched_barrier(0); }
#define BARRIER()    { __builtin_amdgcn_s_barrier(); __builtin_amdgcn_sched_barrier(0); }

// byte offset in a [rows][64 bf16] LDS tile (128 B/row), hash-swizzled.
__device__ __forceinline__ int swzh(int row, int kb) {
  return row * 128 + (kb ^ (((row ^ (row >> 3)) & 7) << 4));
}
__device__ __forceinline__ int rowhash(int r) { return (r ^ (r >> 3)) & 7; }

// ---------------------------------------------------------------- zero
__global__ __launch_bounds__(256) void zero_out_kernel(float* __restrict__ out,
                                                       int* __restrict__ counts) {
  const int n4 = TTOK * HDIM / 4;
  f32x4 z = {0.f, 0.f, 0.f, 0.f};
  for (int i = blockIdx.x * 256 + threadIdx.x; i < n4; i += gridDim.x * 256)
    reinterpret_cast<f32x4*>(out)[i] = z;
  if (blockIdx.x == 0 && threadIdx.x < NEXP) counts[threadIdx.x] = 0;
}

// ---------------------------------------------------------------- gating + x->bf16 (fused)
__global__ __launch_bounds__(256) void gating_kernel(const float* __restrict__ x,
                                                     const float* __restrict__ gw,
                                                     unsigned short* __restrict__ xb,
                                                     float* __restrict__ tw,
                                                     int* __restrict__ counts,
                                                     int* __restrict__ list) {
  const int wv = threadIdx.x >> 6;
  const int lane = threadIdx.x & 63;
  const int t = blockIdx.x * 4 + wv;

  float acc[NEXP];
#pragma unroll
  for (int e = 0; e < NEXP; ++e) acc[e] = 0.f;

  const float* xr = x + (size_t)t * HDIM;
  unsigned short* xbr = xb + (size_t)t * HDIM;
#pragma unroll
  for (int j = 0; j < HDIM / 256; ++j) {
    f32x4 xv = *reinterpret_cast<const f32x4*>(xr + j * 256 + lane * 4);
    u16x4 o;
    o[0] = f2b(xv[0]); o[1] = f2b(xv[1]); o[2] = f2b(xv[2]); o[3] = f2b(xv[3]);
    *reinterpret_cast<u16x4*>(xbr + j * 256 + lane * 4) = o;
#pragma unroll
    for (int e = 0; e < NEXP; ++e) {
      f32x4 gv = *reinterpret_cast<const f32x4*>(gw + (size_t)e * HDIM + j * 256 + lane * 4);
      acc[e] = fmaf(xv[0], gv[0], acc[e]);
      acc[e] = fmaf(xv[1], gv[1], acc[e]);
      acc[e] = fmaf(xv[2], gv[2], acc[e]);
      acc[e] = fmaf(xv[3], gv[3], acc[e]);
    }
  }
#pragma unroll
  for (int e = 0; e < NEXP; ++e) {
#pragma unroll
    for (int off = 32; off; off >>= 1) acc[e] += __shfl_xor(acc[e], off);
  }
  // top-2 (ties -> lowest index, matching lax.top_k)
  int i0 = 0; float s0 = acc[0];
#pragma unroll
  for (int e = 1; e < NEXP; ++e) { if (acc[e] > s0) { s0 = acc[e]; i0 = e; } }
  int i1 = -1; float s1 = -1e30f;
#pragma unroll
  for (int e = 0; e < NEXP; ++e) { if (e != i0 && acc[e] > s1) { s1 = acc[e]; i1 = e; } }

  if (lane == 0) {
    float r = __expf(s1 - s0);          // <= 1
    float w0 = 1.f / (1.f + r);
    float w1 = r / (1.f + r);
    tw[t * 2 + 0] = w0;
    tw[t * 2 + 1] = w1;
    int p0 = atomicAdd(&counts[i0], 1); list[i0 * TTOK + p0] = t * 2 + 0;
    int p1 = atomicAdd(&counts[i1], 1); list[i1 * TTOK + p1] = t * 2 + 1;
  }
}

// ---------------------------------------------------------------- GEMM1  (BM=128, BN=64, BK=64)
// act[slot, :] = silu(x@wg) * (x@wu) * weight
// A: LDS dbuf via global_load_lds, issued 2 tiles early. B: ping-pong reg
// sets, loads issued 2 tiles early. Counted vmcnt(12) retires exactly the
// previous iteration's 12 VMEM ops -> steady-state loads age ~2 phases.
__global__ __launch_bounds__(256, 3) void gemm1_kernel(
    const unsigned short* __restrict__ xb, const float* __restrict__ wg,
    const float* __restrict__ wu, const int* __restrict__ counts,
    const int* __restrict__ list, const float* __restrict__ tw,
    unsigned short* __restrict__ act) {
  const int bid = blockIdx.x;
  const int e = (bid & 7) + 8 * ((bid >> 3) & 1);
  const int rest = bid >> 4;               // 0..127
  const int mblk = rest & 7;
  const int nblk = rest >> 3;              // 0..15
  const int cnt = counts[e];
  const int m0 = mblk * 128;
  if (m0 >= cnt) return;
  const int n0 = nblk * 64;

  __shared__ __align__(16) char As[2 * 128 * 128];  // 2 x [128 m][64 k] bf16, 32 KB
  __shared__ __align__(16) char Bgs[64 * 128];      // [64 n][64 k] bf16, 8 KB
  __shared__ __align__(16) char Bus[64 * 128];
  __shared__ int slot_s[128];
  __shared__ float ws_s[128];

  const int tid = threadIdx.x;
  if (tid < 128) {
    int mr = m0 + tid;
    int mrc = mr < cnt ? mr : cnt - 1;
    int slot = list[e * TTOK + mrc];
    slot_s[tid] = slot;
    ws_s[tid] = tw[slot];
  }
  __syncthreads();

  const int lane = tid & 63;
  const int wv = tid >> 6;

  const unsigned short* agsrc[4];
#pragma unroll
  for (int i = 0; i < 4; ++i) {
    const int r = i * 32 + wv * 8 + (lane >> 3);
    agsrc[i] = xb + (size_t)(slot_s[r] >> 1) * HDIM + ((lane & 7) ^ rowhash(r)) * 8;
  }
  const int adst = wv * 8 * 128;

  const int nq4 = (tid & 15) * 4;
  const int kg4 = (tid >> 4) * 4;
  const float* bgp = wg + (size_t)e * (HDIM * IDIM) + (size_t)kg4 * IDIM + n0 + nq4;
  const float* bup = wu + (size_t)e * (HDIM * IDIM) + (size_t)kg4 * IDIM + n0 + nq4;

  const int wm = (wv >> 1) * 64;
  const int wn = (wv & 1) * 32;
  const int fr = lane & 15;
  const int fk = lane >> 4;

  f32x4 accg[4][2], accu[4][2];
#pragma unroll
  for (int mi = 0; mi < 4; ++mi)
#pragma unroll
    for (int ni = 0; ni < 2; ++ni) {
      accg[mi][ni] = (f32x4){0.f, 0.f, 0.f, 0.f};
      accu[mi][ni] = (f32x4){0.f, 0.f, 0.f, 0.f};
    }

  // two B register sets (ping-pong, compile-time indexed)
  f32x4 rg0[4], ru0[4], rg1[4], ru1[4];
  auto stageA = [&](int kelem, int bufo) {
#pragma unroll
    for (int i = 0; i < 4; ++i)
      __builtin_amdgcn_global_load_lds(
          (const __attribute__((address_space(1))) unsigned int*)(agsrc[i] + kelem),
          (__attribute__((address_space(3))) unsigned int*)(As + bufo + adst + i * 4096),
          16, 0, 0);
  };
  auto loadB0 = [&](int k) {
#pragma unroll
    for (int i = 0; i < 4; ++i) {
      rg0[i] = *reinterpret_cast<const f32x4*>(bgp + (size_t)(k + i) * IDIM);
      ru0[i] = *reinterpret_cast<const f32x4*>(bup + (size_t)(k + i) * IDIM);
    }
  };
  auto loadB1 = [&](int k) {
#pragma unroll
    for (int i = 0; i < 4; ++i) {
      rg1[i] = *reinterpret_cast<const f32x4*>(bgp + (size_t)(k + i) * IDIM);
      ru1[i] = *reinterpret_cast<const f32x4*>(bup + (size_t)(k + i) * IDIM);
    }
  };
  auto writeB0 = [&]() {
#pragma unroll
    for (int c = 0; c < 4; ++c) {
      u16x4 tg, tu;
#pragma unroll
      for (int i = 0; i < 4; ++i) { tg[i] = f2b(rg0[i][c]); tu[i] = f2b(ru0[i][c]); }
      const int wb = swzh(nq4 + c, kg4 * 2);
      *reinterpret_cast<u16x4*>(Bgs + wb) = tg;
      *reinterpret_cast<u16x4*>(Bus + wb) = tu;
    }
  };
  auto writeB1 = [&]() {
#pragma unroll
    for (int c = 0; c < 4; ++c) {
      u16x4 tg, tu;
#pragma unroll
      for (int i = 0; i < 4; ++i) { tg[i] = f2b(rg1[i][c]); tu[i] = f2b(ru1[i][c]); }
      const int wb = swzh(nq4 + c, kg4 * 2);
      *reinterpret_cast<u16x4*>(Bgs + wb) = tg;
      *reinterpret_cast<u16x4*>(Bus + wb) = tu;
    }
  };
  auto compute = [&](int abuf) {
#pragma unroll
    for (int ks = 0; ks < 2; ++ks) {
      const int kb = ks * 64 + fk * 16;
      bf16x8 a[4], bg[2], bu[2];
#pragma unroll
      for (int mi = 0; mi < 4; ++mi)
        a[mi] = *reinterpret_cast<const bf16x8*>(As + abuf + swzh(wm + mi * 16 + fr, kb));
#pragma unroll
      for (int ni = 0; ni < 2; ++ni) {
        bg[ni] = *reinterpret_cast<const bf16x8*>(Bgs + swzh(wn + ni * 16 + fr, kb));
        bu[ni] = *reinterpret_cast<const bf16x8*>(Bus + swzh(wn + ni * 16 + fr, kb));
      }
      __builtin_amdgcn_s_setprio(1);
#pragma unroll
      for (int mi = 0; mi < 4; ++mi)
#pragma unroll
        for (int ni = 0; ni < 2; ++ni) {
          accg[mi][ni] = __builtin_amdgcn_mfma_f32_16x16x32_bf16(a[mi], bg[ni], accg[mi][ni], 0, 0, 0);
          accu[mi][ni] = __builtin_amdgcn_mfma_f32_16x16x32_bf16(a[mi], bu[ni], accu[mi][ni], 0, 0, 0);
        }
      __builtin_amdgcn_s_setprio(0);
    }
  };

  // prologue: A(0),A(1) DMA'd; B(0) via reg set 0 -> LDS; B(1) into reg set 1.
  stageA(0, 0);
  stageA(64, 16384);
  loadB0(0);
  WAIT_VM0();
  writeB0();
  WAIT_LGKM0();
  BARRIER();
  loadB1(64);

  const int NT = HDIM / 64;  // 32
#pragma unroll 1
  for (int t = 0; t < NT; ++t) {
    compute((t & 1) * 16384);
    BARRIER();                            // all waves done reading B and As[t&1]
    const bool more = (t + 2 < NT);
    if (more) {
      stageA((t + 2) * 64, (t & 1) * 16384);  // 4 VMEM into freed A buffer
      if (t & 1) loadB1((t + 2) * 64);        // 8 VMEM into reg set (t&1)
      else       loadB0((t + 2) * 64);
      WAIT_VM12();                        // retire exactly prev iter's 12 ops
    } else {
      WAIT_VM0();                         // tail: nothing younger in flight
    }
    if (t + 1 < NT) {
      if (t & 1) writeB0();               // B(t+1) regs -> LDS (set (t+1)&1)
      else       writeB1();
    }
    WAIT_LGKM0();
    BARRIER();                            // publish B(t+1); A(t+1) drained
  }

  // epilogue: silu(g)*u*w -> bf16 act
#pragma unroll
  for (int mi = 0; mi < 4; ++mi)
#pragma unroll
    for (int ni = 0; ni < 2; ++ni)
#pragma unroll
      for (int r = 0; r < 4; ++r) {
        const int trow = wm + mi * 16 + fk * 4 + r;
        if (m0 + trow < cnt) {
          const int col = n0 + wn + ni * 16 + fr;
          const float g = accg[mi][ni][r];
          const float u = accu[mi][ni][r];
          const float a = (g / (1.f + __expf(-g))) * u * ws_s[trow];
          act[(size_t)slot_s[trow] * IDIM + col] = f2b(a);
        }
      }
}

// ---------------------------------------------------------------- GEMM2  (BM=128, BN=128, BK=64)
// out[token, :] += act[slot, :] @ wd[e] — same deep-pipelined scheme.
__global__ __launch_bounds__(256, 3) void gemm2_kernel(
    const unsigned short* __restrict__ act, const float* __restrict__ wd,
    const int* __restrict__ counts, const int* __restrict__ list,
    float* __restrict__ out) {
  const int bid = blockIdx.x;
  const int e = (bid & 7) + 8 * ((bid >> 3) & 1);
  const int rest = bid >> 4;               // 0..127
  const int mblk = rest & 7;
  const int nblk = rest >> 3;              // 0..15
  const int cnt = counts[e];
  const int m0 = mblk * 128;
  if (m0 >= cnt) return;
  const int n0 = nblk * 128;

  __shared__ __align__(16) char As[2 * 128 * 128];  // 32 KB
  __shared__ __align__(16) char Bs[128 * 128];      // [128 n][64 k], 16 KB
  __shared__ int slot_s[128];

  const int tid = threadIdx.x;
  if (tid < 128) {
    int mr = m0 + tid;
    int mrc = mr < cnt ? mr : cnt - 1;
    slot_s[tid] = list[e * TTOK + mrc];
  }
  __syncthreads();

  const int lane = tid & 63;
  const int wv = tid >> 6;

  const unsigned short* agsrc[4];
#pragma unroll
  for (int i = 0; i < 4; ++i) {
    const int r = i * 32 + wv * 8 + (lane >> 3);
    agsrc[i] = act + (size_t)slot_s[r] * IDIM + ((lane & 7) ^ rowhash(r)) * 8;
  }
  const int adst = wv * 8 * 128;

  const int nq4 = (tid & 31) * 4;          // n 0..127
  const int kg4 = (tid >> 5) * 4;          // k 0..31 (+32 for h=1)
  const float* bdp = wd + (size_t)e * (IDIM * HDIM) + (size_t)kg4 * HDIM + n0 + nq4;

  const int wm = (wv >> 1) * 64;
  const int wn = (wv & 1) * 64;
  const int fr = lane & 15;
  const int fk = lane >> 4;

  f32x4 acc[4][4];
#pragma unroll
  for (int mi = 0; mi < 4; ++mi)
#pragma unroll
    for (int ni = 0; ni < 4; ++ni) acc[mi][ni] = (f32x4){0.f, 0.f, 0.f, 0.f};

  f32x4 rb0[2][4], rb1[2][4];
  auto stageA = [&](int kelem, int bufo) {
#pragma unroll
    for (int i = 0; i < 4; ++i)
      __builtin_amdgcn_global_load_lds(
          (const __attribute__((address_space(1))) unsigned int*)(agsrc[i] + kelem),
          (__attribute__((address_space(3))) unsigned int*)(As + bufo + adst + i * 4096),
          16, 0, 0);
  };
  auto loadB0 = [&](int k) {
#pragma unroll
    for (int h = 0; h < 2; ++h)
#pragma unroll
      for (int i = 0; i < 4; ++i)
        rb0[h][i] = *reinterpret_cast<const f32x4*>(bdp + (size_t)(k + 32 * h + i) * HDIM);
  };
  auto loadB1 = [&](int k) {
#pragma unroll
    for (int h = 0; h < 2; ++h)
#pragma unroll
      for (int i = 0; i < 4; ++i)
        rb1[h][i] = *reinterpret_cast<const f32x4*>(bdp + (size_t)(k + 32 * h + i) * HDIM);
  };
  auto writeB0 = [&]() {
#pragma unroll
    for (int h = 0; h < 2; ++h)
#pragma unroll
      for (int c = 0; c < 4; ++c) {
        u16x4 tb;
#pragma unroll
        for (int i = 0; i < 4; ++i) tb[i] = f2b(rb0[h][i][c]);
        *reinterpret_cast<u16x4*>(Bs + swzh(nq4 + c, (kg4 + 32 * h) * 2)) = tb;
      }
  };
  auto writeB1 = [&]() {
#pragma unroll
    for (int h = 0; h < 2; ++h)
#pragma unroll
      for (int c = 0; c < 4; ++c) {
        u16x4 tb;
#pragma unroll
        for (int i = 0; i < 4; ++i) tb[i] = f2b(rb1[h][i][c]);
        *reinterpret_cast<u16x4*>(Bs + swzh(nq4 + c, (kg4 + 32 * h) * 2)) = tb;
      }
  };
  auto compute = [&](int abuf) {
#pragma unroll
    for (int ks = 0; ks < 2; ++ks) {
      const int kb = ks * 64 + fk * 16;
      bf16x8 a[4], b[4];
#pragma unroll
      for (int mi = 0; mi < 4; ++mi)
        a[mi] = *reinterpret_cast<const bf16x8*>(As + abuf + swzh(wm + mi * 16 + fr, kb));
#pragma unroll
      for (int ni = 0; ni < 4; ++ni)
        b[ni] = *reinterpret_cast<const bf16x8*>(Bs + swzh(wn + ni * 16 + fr, kb));
      __builtin_amdgcn_s_setprio(1);
#pragma unroll
      for (int mi = 0; mi < 4; ++mi)
#pragma unroll
        for (int ni = 0; ni < 4; ++ni)
          acc[mi][ni] = __builtin_amdgcn_mfma_f32_16x16x32_bf16(a[mi], b[ni], acc[mi][ni], 0, 0, 0);
      __builtin_amdgcn_s_setprio(0);
    }
  };

  stageA(0, 0);
  stageA(64, 16384);
  loadB0(0);
  WAIT_VM0();
  writeB0();
  WAIT_LGKM0();
  BARRIER();
  loadB1(64);

  const int NT = IDIM / 64;  // 16
#pragma unroll 1
  for (int t = 0; t < NT; ++t) {
    compute((t & 1) * 16384);
    BARRIER();
    const bool more = (t + 2 < NT);
    if (more) {
      stageA((t + 2) * 64, (t & 1) * 16384);
      if (t & 1) loadB1((t + 2) * 64);
      else       loadB0((t + 2) * 64);
      WAIT_VM12();
    } else {
      WAIT_VM0();
    }
    if (t + 1 < NT) {
      if (t & 1) writeB0();
      else       writeB1();
    }
    WAIT_LGKM0();
    BARRIER();
  }

#pragma unroll
  for (int mi = 0; mi < 4; ++mi)
#pragma unroll
    for (int ni = 0; ni < 4; ++ni)
#pragma unroll
      for (int r = 0; r < 4; ++r) {
        const int trow = wm + mi * 16 + fk * 4 + r;
        if (m0 + trow < cnt) {
          const int t = slot_s[trow] >> 1;
          const int col = n0 + wn + ni * 16 + fr;
          atomicAdd(&out[(size_t)t * HDIM + col], acc[mi][ni][r]);
        }
      }
}

// ---------------------------------------------------------------- launch
extern "C" void kernel_launch(void* const* d_in, const int* in_sizes, int n_in,
                              void* d_out, int out_size, void* d_ws, size_t ws_size,
                              hipStream_t stream) {
  const float* x = (const float*)d_in[0];
  const float* gate_w = (const float*)d_in[1];
  const float* wg = (const float*)d_in[2];
  const float* wu = (const float*)d_in[3];
  const float* wd = (const float*)d_in[4];
  float* out = (float*)d_out;

  char* w = (char*)d_ws;
  size_t off = 0;
  unsigned short* xb = (unsigned short*)(w + off); off += (size_t)TTOK * HDIM * 2;
  unsigned short* act = (unsigned short*)(w + off); off += (size_t)TTOK * KTOP * IDIM * 2;
  float* tw = (float*)(w + off); off += (size_t)TTOK * KTOP * 4;
  int* counts = (int*)(w + off); off += 256;
  int* list = (int*)(w + off); off += (size_t)NEXP * TTOK * 4;

  zero_out_kernel<<<2048, 256, 0, stream>>>(out, counts);
  gating_kernel<<<TTOK / 4, 256, 0, stream>>>(x, gate_w, xb, tw, counts, list);
  // gemm1: 16 e x 8 m x 16 n = 2048 blocks (XCD-clustered decode in-kernel)
  gemm1_kernel<<<2048, 256, 0, stream>>>(xb, wg, wu, counts, list, tw, act);
  // gemm2: 16 e x 8 m x 16 n = 2048 blocks
  gemm2_kernel<<<2048, 256, 0, stream>>>(act, wd, counts, list, out);
}

// Round 12
// 495.798 us; speedup vs baseline: 1.8445x; 1.8445x over previous
//
#include <hip/hip_runtime.h>
#include <hip/hip_bf16.h>

#define HDIM 2048
#define IDIM 1024
#define NEXP 16
#define TTOK 4096   // B*S tokens
#define KTOP 2

typedef __attribute__((ext_vector_type(4))) float f32x4;
typedef __attribute__((ext_vector_type(8))) short bf16x8;
typedef __attribute__((ext_vector_type(4))) unsigned short u16x4;

__device__ __forceinline__ unsigned short f2b(float f) {
  __hip_bfloat16 h = __float2bfloat16(f);
  return *reinterpret_cast<unsigned short*>(&h);
}

// phase-boundary primitives
#define WAIT_VM0()   { asm volatile("s_waitcnt vmcnt(0)" ::: "memory"); __builtin_amdgcn_sched_barrier(0); }
#define WAIT_LGKM0() { asm volatile("s_waitcnt lgkmcnt(0)" ::: "memory"); __builtin_amdgcn_sched_barrier(0); }
#define BARRIER()    { __builtin_amdgcn_s_barrier(); __builtin_amdgcn_sched_barrier(0); }

// byte offset in a [rows][64 bf16] LDS tile (128 B/row), hash-swizzled.
__device__ __forceinline__ int swzh(int row, int kb) {
  return row * 128 + (kb ^ (((row ^ (row >> 3)) & 7) << 4));
}
__device__ __forceinline__ int rowhash(int r) { return (r ^ (r >> 3)) & 7; }

// ---------------------------------------------------------------- gating + x->bf16 (fused)
// builds: combined per-expert list (for gemm1), primary list0 (top-1) and
// secondary list1 (top-2) for the two gemm2 passes.
__global__ __launch_bounds__(256) void gating_kernel(const float* __restrict__ x,
                                                     const float* __restrict__ gw,
                                                     unsigned short* __restrict__ xb,
                                                     float* __restrict__ tw,
                                                     int* __restrict__ cnts,  // [0:16)=comb, [16:32)=prim, [32:48)=sec
                                                     int* __restrict__ list,
                                                     int* __restrict__ list0,
                                                     int* __restrict__ list1) {
  const int wv = threadIdx.x >> 6;
  const int lane = threadIdx.x & 63;
  const int t = blockIdx.x * 4 + wv;

  float acc[NEXP];
#pragma unroll
  for (int e = 0; e < NEXP; ++e) acc[e] = 0.f;

  const float* xr = x + (size_t)t * HDIM;
  unsigned short* xbr = xb + (size_t)t * HDIM;
#pragma unroll
  for (int j = 0; j < HDIM / 256; ++j) {
    f32x4 xv = *reinterpret_cast<const f32x4*>(xr + j * 256 + lane * 4);
    u16x4 o;
    o[0] = f2b(xv[0]); o[1] = f2b(xv[1]); o[2] = f2b(xv[2]); o[3] = f2b(xv[3]);
    *reinterpret_cast<u16x4*>(xbr + j * 256 + lane * 4) = o;
#pragma unroll
    for (int e = 0; e < NEXP; ++e) {
      f32x4 gv = *reinterpret_cast<const f32x4*>(gw + (size_t)e * HDIM + j * 256 + lane * 4);
      acc[e] = fmaf(xv[0], gv[0], acc[e]);
      acc[e] = fmaf(xv[1], gv[1], acc[e]);
      acc[e] = fmaf(xv[2], gv[2], acc[e]);
      acc[e] = fmaf(xv[3], gv[3], acc[e]);
    }
  }
#pragma unroll
  for (int e = 0; e < NEXP; ++e) {
#pragma unroll
    for (int off = 32; off; off >>= 1) acc[e] += __shfl_xor(acc[e], off);
  }
  // top-2 (ties -> lowest index, matching lax.top_k)
  int i0 = 0; float s0 = acc[0];
#pragma unroll
  for (int e = 1; e < NEXP; ++e) { if (acc[e] > s0) { s0 = acc[e]; i0 = e; } }
  int i1 = -1; float s1 = -1e30f;
#pragma unroll
  for (int e = 0; e < NEXP; ++e) { if (e != i0 && acc[e] > s1) { s1 = acc[e]; i1 = e; } }

  if (lane == 0) {
    float r = __expf(s1 - s0);          // <= 1
    float w0 = 1.f / (1.f + r);
    float w1 = r / (1.f + r);
    tw[t * 2 + 0] = w0;
    tw[t * 2 + 1] = w1;
    int p0 = atomicAdd(&cnts[i0], 1); list[i0 * TTOK + p0] = t * 2 + 0;
    int p1 = atomicAdd(&cnts[i1], 1); list[i1 * TTOK + p1] = t * 2 + 1;
    int q0 = atomicAdd(&cnts[16 + i0], 1); list0[i0 * TTOK + q0] = t * 2 + 0;
    int q1 = atomicAdd(&cnts[32 + i1], 1); list1[i1 * TTOK + q1] = t * 2 + 1;
  }
}

// ---------------------------------------------------------------- GEMM1  (BM=128, BN=64, BK=64)
// act[slot, :] = silu(x@wg) * (x@wu) * weight   (identical to passing R10)
__global__ __launch_bounds__(256, 3) void gemm1_kernel(
    const unsigned short* __restrict__ xb, const float* __restrict__ wg,
    const float* __restrict__ wu, const int* __restrict__ counts,
    const int* __restrict__ list, const float* __restrict__ tw,
    unsigned short* __restrict__ act) {
  const int bid = blockIdx.x;
  const int e = (bid & 7) + 8 * ((bid >> 3) & 1);
  const int rest = bid >> 4;               // 0..127
  const int mblk = rest & 7;
  const int nblk = rest >> 3;              // 0..15
  const int cnt = counts[e];
  const int m0 = mblk * 128;
  if (m0 >= cnt) return;
  const int n0 = nblk * 64;

  __shared__ __align__(16) char As[2 * 128 * 128];  // 2 x [128 m][64 k] bf16, 32 KB
  __shared__ __align__(16) char Bgs[64 * 128];      // [64 n][64 k] bf16, 8 KB
  __shared__ __align__(16) char Bus[64 * 128];
  __shared__ int slot_s[128];
  __shared__ float ws_s[128];

  const int tid = threadIdx.x;
  if (tid < 128) {
    int mr = m0 + tid;
    int mrc = mr < cnt ? mr : cnt - 1;
    int slot = list[e * TTOK + mrc];
    slot_s[tid] = slot;
    ws_s[tid] = tw[slot];
  }
  __syncthreads();

  const int lane = tid & 63;
  const int wv = tid >> 6;

  const unsigned short* agsrc[4];
#pragma unroll
  for (int i = 0; i < 4; ++i) {
    const int r = i * 32 + wv * 8 + (lane >> 3);
    agsrc[i] = xb + (size_t)(slot_s[r] >> 1) * HDIM + ((lane & 7) ^ rowhash(r)) * 8;
  }
  const int adst = wv * 8 * 128;

  const int nq4 = (tid & 15) * 4;
  const int kg4 = (tid >> 4) * 4;
  const float* bgp = wg + (size_t)e * (HDIM * IDIM) + (size_t)kg4 * IDIM + n0 + nq4;
  const float* bup = wu + (size_t)e * (HDIM * IDIM) + (size_t)kg4 * IDIM + n0 + nq4;

  const int wm = (wv >> 1) * 64;
  const int wn = (wv & 1) * 32;
  const int fr = lane & 15;
  const int fk = lane >> 4;

  f32x4 accg[4][2], accu[4][2];
#pragma unroll
  for (int mi = 0; mi < 4; ++mi)
#pragma unroll
    for (int ni = 0; ni < 2; ++ni) {
      accg[mi][ni] = (f32x4){0.f, 0.f, 0.f, 0.f};
      accu[mi][ni] = (f32x4){0.f, 0.f, 0.f, 0.f};
    }

  f32x4 rg[4], ru[4];
  auto stageA = [&](int kelem, int bufo) {
#pragma unroll
    for (int i = 0; i < 4; ++i)
      __builtin_amdgcn_global_load_lds(
          (const __attribute__((address_space(1))) unsigned int*)(agsrc[i] + kelem),
          (__attribute__((address_space(3))) unsigned int*)(As + bufo + adst + i * 4096),
          16, 0, 0);
  };
  auto loadB = [&](int k) {
#pragma unroll
    for (int i = 0; i < 4; ++i) {
      rg[i] = *reinterpret_cast<const f32x4*>(bgp + (size_t)(k + i) * IDIM);
      ru[i] = *reinterpret_cast<const f32x4*>(bup + (size_t)(k + i) * IDIM);
    }
  };
  auto writeB = [&]() {
#pragma unroll
    for (int c = 0; c < 4; ++c) {
      u16x4 tg, tu;
#pragma unroll
      for (int i = 0; i < 4; ++i) { tg[i] = f2b(rg[i][c]); tu[i] = f2b(ru[i][c]); }
      const int wb = swzh(nq4 + c, kg4 * 2);
      *reinterpret_cast<u16x4*>(Bgs + wb) = tg;
      *reinterpret_cast<u16x4*>(Bus + wb) = tu;
    }
  };
  auto compute = [&](int abuf) {
#pragma unroll
    for (int ks = 0; ks < 2; ++ks) {
      const int kb = ks * 64 + fk * 16;
      bf16x8 a[4], bg[2], bu[2];
#pragma unroll
      for (int mi = 0; mi < 4; ++mi)
        a[mi] = *reinterpret_cast<const bf16x8*>(As + abuf + swzh(wm + mi * 16 + fr, kb));
#pragma unroll
      for (int ni = 0; ni < 2; ++ni) {
        bg[ni] = *reinterpret_cast<const bf16x8*>(Bgs + swzh(wn + ni * 16 + fr, kb));
        bu[ni] = *reinterpret_cast<const bf16x8*>(Bus + swzh(wn + ni * 16 + fr, kb));
      }
      __builtin_amdgcn_s_setprio(1);
#pragma unroll
      for (int mi = 0; mi < 4; ++mi)
#pragma unroll
        for (int ni = 0; ni < 2; ++ni) {
          accg[mi][ni] = __builtin_amdgcn_mfma_f32_16x16x32_bf16(a[mi], bg[ni], accg[mi][ni], 0, 0, 0);
          accu[mi][ni] = __builtin_amdgcn_mfma_f32_16x16x32_bf16(a[mi], bu[ni], accu[mi][ni], 0, 0, 0);
        }
      __builtin_amdgcn_s_setprio(0);
    }
  };

  stageA(0, 0);
  stageA(64, 16384);
  loadB(0);
  WAIT_VM0();
  writeB();
  WAIT_LGKM0();
  BARRIER();
  loadB(64);

  const int NT = HDIM / 64;  // 32
#pragma unroll 1
  for (int t = 0; t < NT; ++t) {
    compute((t & 1) * 16384);
    WAIT_LGKM0();
    BARRIER();
    if (t + 1 < NT) {
      WAIT_VM0();
      writeB();
    }
    if (t + 2 < NT) stageA((t + 2) * 64, (t & 1) * 16384);
    WAIT_LGKM0();
    BARRIER();
    if (t + 2 < NT) loadB((t + 2) * 64);
  }

#pragma unroll
  for (int mi = 0; mi < 4; ++mi)
#pragma unroll
    for (int ni = 0; ni < 2; ++ni)
#pragma unroll
      for (int r = 0; r < 4; ++r) {
        const int trow = wm + mi * 16 + fk * 4 + r;
        if (m0 + trow < cnt) {
          const int col = n0 + wn + ni * 16 + fr;
          const float g = accg[mi][ni][r];
          const float u = accu[mi][ni][r];
          const float a = (g / (1.f + __expf(-g))) * u * ws_s[trow];
          act[(size_t)slot_s[trow] * IDIM + col] = f2b(a);
        }
      }
}

// ---------------------------------------------------------------- GEMM2  (BM=128, BN=128, BK=64)
// out[token, :] {=, +=} act[slot, :] @ wd[e] — no atomics:
// add_mode=0 (primary list): plain store (replaces zero-init);
// add_mode=1 (secondary list): load+add+store (sole writer per element).
__global__ __launch_bounds__(256, 3) void gemm2_kernel(
    const unsigned short* __restrict__ act, const float* __restrict__ wd,
    const int* __restrict__ counts2, const int* __restrict__ list2,
    float* __restrict__ out, int add_mode) {
  const int bid = blockIdx.x;
  const int e = (bid & 7) + 8 * ((bid >> 3) & 1);
  const int rest = bid >> 4;               // 0..127
  const int mblk = rest & 7;
  const int nblk = rest >> 3;              // 0..15
  const int cnt = counts2[e];
  const int m0 = mblk * 128;
  if (m0 >= cnt) return;
  const int n0 = nblk * 128;

  __shared__ __align__(16) char As[2 * 128 * 128];  // 32 KB
  __shared__ __align__(16) char Bs[128 * 128];      // [128 n][64 k], 16 KB
  __shared__ int slot_s[128];

  const int tid = threadIdx.x;
  if (tid < 128) {
    int mr = m0 + tid;
    int mrc = mr < cnt ? mr : cnt - 1;
    slot_s[tid] = list2[e * TTOK + mrc];
  }
  __syncthreads();

  const int lane = tid & 63;
  const int wv = tid >> 6;

  const unsigned short* agsrc[4];
#pragma unroll
  for (int i = 0; i < 4; ++i) {
    const int r = i * 32 + wv * 8 + (lane >> 3);
    agsrc[i] = act + (size_t)slot_s[r] * IDIM + ((lane & 7) ^ rowhash(r)) * 8;
  }
  const int adst = wv * 8 * 128;

  const int nq4 = (tid & 31) * 4;          // n 0..127
  const int kg4 = (tid >> 5) * 4;          // k 0..31 (+32 for h=1)
  const float* bdp = wd + (size_t)e * (IDIM * HDIM) + (size_t)kg4 * HDIM + n0 + nq4;

  const int wm = (wv >> 1) * 64;
  const int wn = (wv & 1) * 64;
  const int fr = lane & 15;
  const int fk = lane >> 4;

  f32x4 acc[4][4];
#pragma unroll
  for (int mi = 0; mi < 4; ++mi)
#pragma unroll
    for (int ni = 0; ni < 4; ++ni) acc[mi][ni] = (f32x4){0.f, 0.f, 0.f, 0.f};

  f32x4 rb[2][4];
  auto stageA = [&](int kelem, int bufo) {
#pragma unroll
    for (int i = 0; i < 4; ++i)
      __builtin_amdgcn_global_load_lds(
          (const __attribute__((address_space(1))) unsigned int*)(agsrc[i] + kelem),
          (__attribute__((address_space(3))) unsigned int*)(As + bufo + adst + i * 4096),
          16, 0, 0);
  };
  auto loadB = [&](int k) {
#pragma unroll
    for (int h = 0; h < 2; ++h)
#pragma unroll
      for (int i = 0; i < 4; ++i)
        rb[h][i] = *reinterpret_cast<const f32x4*>(bdp + (size_t)(k + 32 * h + i) * HDIM);
  };
  auto writeB = [&]() {
#pragma unroll
    for (int h = 0; h < 2; ++h)
#pragma unroll
      for (int c = 0; c < 4; ++c) {
        u16x4 tb;
#pragma unroll
        for (int i = 0; i < 4; ++i) tb[i] = f2b(rb[h][i][c]);
        *reinterpret_cast<u16x4*>(Bs + swzh(nq4 + c, (kg4 + 32 * h) * 2)) = tb;
      }
  };
  auto compute = [&](int abuf) {
#pragma unroll
    for (int ks = 0; ks < 2; ++ks) {
      const int kb = ks * 64 + fk * 16;
      bf16x8 a[4], b[4];
#pragma unroll
      for (int mi = 0; mi < 4; ++mi)
        a[mi] = *reinterpret_cast<const bf16x8*>(As + abuf + swzh(wm + mi * 16 + fr, kb));
#pragma unroll
      for (int ni = 0; ni < 4; ++ni)
        b[ni] = *reinterpret_cast<const bf16x8*>(Bs + swzh(wn + ni * 16 + fr, kb));
      __builtin_amdgcn_s_setprio(1);
#pragma unroll
      for (int mi = 0; mi < 4; ++mi)
#pragma unroll
        for (int ni = 0; ni < 4; ++ni)
          acc[mi][ni] = __builtin_amdgcn_mfma_f32_16x16x32_bf16(a[mi], b[ni], acc[mi][ni], 0, 0, 0);
      __builtin_amdgcn_s_setprio(0);
    }
  };

  stageA(0, 0);
  stageA(64, 16384);
  loadB(0);
  WAIT_VM0();
  writeB();
  WAIT_LGKM0();
  BARRIER();
  loadB(64);

  const int NT = IDIM / 64;  // 16
#pragma unroll 1
  for (int t = 0; t < NT; ++t) {
    compute((t & 1) * 16384);
    WAIT_LGKM0();
    BARRIER();
    if (t + 1 < NT) {
      WAIT_VM0();
      writeB();
    }
    if (t + 2 < NT) stageA((t + 2) * 64, (t & 1) * 16384);
    WAIT_LGKM0();
    BARRIER();
    if (t + 2 < NT) loadB((t + 2) * 64);
  }

#pragma unroll
  for (int mi = 0; mi < 4; ++mi)
#pragma unroll
    for (int ni = 0; ni < 4; ++ni)
#pragma unroll
      for (int r = 0; r < 4; ++r) {
        const int trow = wm + mi * 16 + fk * 4 + r;
        if (m0 + trow < cnt) {
          const int tok = slot_s[trow] >> 1;
          const int col = n0 + wn + ni * 16 + fr;
          float* p = &out[(size_t)tok * HDIM + col];
          float v = acc[mi][ni][r];
          if (add_mode) v += *p;          // sole writer: plain RMW, no atomic
          *p = v;
        }
      }
}

// ---------------------------------------------------------------- launch
extern "C" void kernel_launch(void* const* d_in, const int* in_sizes, int n_in,
                              void* d_out, int out_size, void* d_ws, size_t ws_size,
                              hipStream_t stream) {
  const float* x = (const float*)d_in[0];
  const float* gate_w = (const float*)d_in[1];
  const float* wg = (const float*)d_in[2];
  const float* wu = (const float*)d_in[3];
  const float* wd = (const float*)d_in[4];
  float* out = (float*)d_out;

  char* w = (char*)d_ws;
  size_t off = 0;
  unsigned short* xb = (unsigned short*)(w + off); off += (size_t)TTOK * HDIM * 2;
  unsigned short* act = (unsigned short*)(w + off); off += (size_t)TTOK * KTOP * IDIM * 2;
  float* tw = (float*)(w + off); off += (size_t)TTOK * KTOP * 4;
  int* cnts = (int*)(w + off); off += 256;                     // [comb16|prim16|sec16]
  int* list  = (int*)(w + off); off += (size_t)NEXP * TTOK * 4;
  int* list0 = (int*)(w + off); off += (size_t)NEXP * TTOK * 4;
  int* list1 = (int*)(w + off); off += (size_t)NEXP * TTOK * 4;

  hipMemsetAsync(cnts, 0, 256, stream);
  gating_kernel<<<TTOK / 4, 256, 0, stream>>>(x, gate_w, xb, tw, cnts, list, list0, list1);
  // gemm1: 16 e x 8 m x 16 n = 2048 blocks (XCD-clustered decode in-kernel)
  gemm1_kernel<<<2048, 256, 0, stream>>>(xb, wg, wu, cnts, list, tw, act);
  // gemm2 pass A (primary slots): plain stores, covers every out element
  gemm2_kernel<<<2048, 256, 0, stream>>>(act, wd, cnts + 16, list0, out, 0);
  // gemm2 pass B (secondary slots): non-atomic read-add-store
  gemm2_kernel<<<2048, 256, 0, stream>>>(act, wd, cnts + 32, list1, out, 1);
}

// Round 13
// 466.961 us; speedup vs baseline: 1.9584x; 1.0618x over previous
//
#include <hip/hip_runtime.h>
#include <hip/hip_bf16.h>

#define HDIM 2048
#define IDIM 1024
#define NEXP 16
#define TTOK 4096   // B*S tokens
#define KTOP 2

typedef __attribute__((ext_vector_type(4))) float f32x4;
typedef __attribute__((ext_vector_type(8))) short bf16x8;
typedef __attribute__((ext_vector_type(4))) unsigned short u16x4;

__device__ __forceinline__ unsigned short f2b(float f) {
  __hip_bfloat16 h = __float2bfloat16(f);
  return *reinterpret_cast<unsigned short*>(&h);
}

// phase-boundary primitives
#define WAIT_VM0()   { asm volatile("s_waitcnt vmcnt(0)" ::: "memory"); __builtin_amdgcn_sched_barrier(0); }
#define WAIT_LGKM0() { asm volatile("s_waitcnt lgkmcnt(0)" ::: "memory"); __builtin_amdgcn_sched_barrier(0); }
#define BARRIER()    { __builtin_amdgcn_s_barrier(); __builtin_amdgcn_sched_barrier(0); }

// byte offset in a [rows][64 bf16] LDS tile (128 B/row), hash-swizzled.
__device__ __forceinline__ int swzh(int row, int kb) {
  return row * 128 + (kb ^ (((row ^ (row >> 3)) & 7) << 4));
}
__device__ __forceinline__ int rowhash(int r) { return (r ^ (r >> 3)) & 7; }

// ---------------------------------------------------------------- gating + x->bf16 (fused)
// EXACT R10 form (2 atomics, combined list) — the R12 4-atomic variant choked
// the register allocator (VGPR 56) and serialized the load pipeline.
__global__ __launch_bounds__(256) void gating_kernel(const float* __restrict__ x,
                                                     const float* __restrict__ gw,
                                                     unsigned short* __restrict__ xb,
                                                     float* __restrict__ tw,
                                                     int* __restrict__ counts,
                                                     int* __restrict__ list) {
  const int wv = threadIdx.x >> 6;
  const int lane = threadIdx.x & 63;
  const int t = blockIdx.x * 4 + wv;

  float acc[NEXP];
#pragma unroll
  for (int e = 0; e < NEXP; ++e) acc[e] = 0.f;

  const float* xr = x + (size_t)t * HDIM;
  unsigned short* xbr = xb + (size_t)t * HDIM;
#pragma unroll
  for (int j = 0; j < HDIM / 256; ++j) {
    f32x4 xv = *reinterpret_cast<const f32x4*>(xr + j * 256 + lane * 4);
    u16x4 o;
    o[0] = f2b(xv[0]); o[1] = f2b(xv[1]); o[2] = f2b(xv[2]); o[3] = f2b(xv[3]);
    *reinterpret_cast<u16x4*>(xbr + j * 256 + lane * 4) = o;
#pragma unroll
    for (int e = 0; e < NEXP; ++e) {
      f32x4 gv = *reinterpret_cast<const f32x4*>(gw + (size_t)e * HDIM + j * 256 + lane * 4);
      acc[e] = fmaf(xv[0], gv[0], acc[e]);
      acc[e] = fmaf(xv[1], gv[1], acc[e]);
      acc[e] = fmaf(xv[2], gv[2], acc[e]);
      acc[e] = fmaf(xv[3], gv[3], acc[e]);
    }
  }
#pragma unroll
  for (int e = 0; e < NEXP; ++e) {
#pragma unroll
    for (int off = 32; off; off >>= 1) acc[e] += __shfl_xor(acc[e], off);
  }
  // top-2 (ties -> lowest index, matching lax.top_k)
  int i0 = 0; float s0 = acc[0];
#pragma unroll
  for (int e = 1; e < NEXP; ++e) { if (acc[e] > s0) { s0 = acc[e]; i0 = e; } }
  int i1 = -1; float s1 = -1e30f;
#pragma unroll
  for (int e = 0; e < NEXP; ++e) { if (e != i0 && acc[e] > s1) { s1 = acc[e]; i1 = e; } }

  if (lane == 0) {
    float r = __expf(s1 - s0);          // <= 1
    float w0 = 1.f / (1.f + r);
    float w1 = r / (1.f + r);
    tw[t * 2 + 0] = w0;
    tw[t * 2 + 1] = w1;
    int p0 = atomicAdd(&counts[i0], 1); list[i0 * TTOK + p0] = t * 2 + 0;
    int p1 = atomicAdd(&counts[i1], 1); list[i1 * TTOK + p1] = t * 2 + 1;
  }
}

// ---------------------------------------------------------------- split
// Partition each expert's combined list into primary (even slot) and
// secondary (odd slot) lists via LDS atomics. 16 blocks, ~3 us.
__global__ __launch_bounds__(256) void split_kernel(const int* __restrict__ cnts,
                                                    const int* __restrict__ list,
                                                    int* __restrict__ cnts2,  // [0:16)=prim, [16:32)=sec
                                                    int* __restrict__ list0,
                                                    int* __restrict__ list1) {
  const int e = blockIdx.x;
  const int cnt = cnts[e];
  __shared__ int c0, c1;
  if (threadIdx.x == 0) { c0 = 0; c1 = 0; }
  __syncthreads();
  for (int i = threadIdx.x; i < cnt; i += 256) {
    int s = list[e * TTOK + i];
    if (s & 1) { int p = atomicAdd(&c1, 1); list1[e * TTOK + p] = s; }
    else       { int p = atomicAdd(&c0, 1); list0[e * TTOK + p] = s; }
  }
  __syncthreads();
  if (threadIdx.x == 0) { cnts2[e] = c0; cnts2[16 + e] = c1; }
}

// ---------------------------------------------------------------- GEMM1  (BM=128, BN=64, BK=64)
// act[slot, :] = silu(x@wg) * (x@wu) * weight   (identical to passing R10)
__global__ __launch_bounds__(256, 3) void gemm1_kernel(
    const unsigned short* __restrict__ xb, const float* __restrict__ wg,
    const float* __restrict__ wu, const int* __restrict__ counts,
    const int* __restrict__ list, const float* __restrict__ tw,
    unsigned short* __restrict__ act) {
  const int bid = blockIdx.x;
  const int e = (bid & 7) + 8 * ((bid >> 3) & 1);
  const int rest = bid >> 4;               // 0..127
  const int mblk = rest & 7;
  const int nblk = rest >> 3;              // 0..15
  const int cnt = counts[e];
  const int m0 = mblk * 128;
  if (m0 >= cnt) return;
  const int n0 = nblk * 64;

  __shared__ __align__(16) char As[2 * 128 * 128];  // 2 x [128 m][64 k] bf16, 32 KB
  __shared__ __align__(16) char Bgs[64 * 128];      // [64 n][64 k] bf16, 8 KB
  __shared__ __align__(16) char Bus[64 * 128];
  __shared__ int slot_s[128];
  __shared__ float ws_s[128];

  const int tid = threadIdx.x;
  if (tid < 128) {
    int mr = m0 + tid;
    int mrc = mr < cnt ? mr : cnt - 1;
    int slot = list[e * TTOK + mrc];
    slot_s[tid] = slot;
    ws_s[tid] = tw[slot];
  }
  __syncthreads();

  const int lane = tid & 63;
  const int wv = tid >> 6;

  const unsigned short* agsrc[4];
#pragma unroll
  for (int i = 0; i < 4; ++i) {
    const int r = i * 32 + wv * 8 + (lane >> 3);
    agsrc[i] = xb + (size_t)(slot_s[r] >> 1) * HDIM + ((lane & 7) ^ rowhash(r)) * 8;
  }
  const int adst = wv * 8 * 128;

  const int nq4 = (tid & 15) * 4;
  const int kg4 = (tid >> 4) * 4;
  const float* bgp = wg + (size_t)e * (HDIM * IDIM) + (size_t)kg4 * IDIM + n0 + nq4;
  const float* bup = wu + (size_t)e * (HDIM * IDIM) + (size_t)kg4 * IDIM + n0 + nq4;

  const int wm = (wv >> 1) * 64;
  const int wn = (wv & 1) * 32;
  const int fr = lane & 15;
  const int fk = lane >> 4;

  f32x4 accg[4][2], accu[4][2];
#pragma unroll
  for (int mi = 0; mi < 4; ++mi)
#pragma unroll
    for (int ni = 0; ni < 2; ++ni) {
      accg[mi][ni] = (f32x4){0.f, 0.f, 0.f, 0.f};
      accu[mi][ni] = (f32x4){0.f, 0.f, 0.f, 0.f};
    }

  f32x4 rg[4], ru[4];
  auto stageA = [&](int kelem, int bufo) {
#pragma unroll
    for (int i = 0; i < 4; ++i)
      __builtin_amdgcn_global_load_lds(
          (const __attribute__((address_space(1))) unsigned int*)(agsrc[i] + kelem),
          (__attribute__((address_space(3))) unsigned int*)(As + bufo + adst + i * 4096),
          16, 0, 0);
  };
  auto loadB = [&](int k) {
#pragma unroll
    for (int i = 0; i < 4; ++i) {
      rg[i] = *reinterpret_cast<const f32x4*>(bgp + (size_t)(k + i) * IDIM);
      ru[i] = *reinterpret_cast<const f32x4*>(bup + (size_t)(k + i) * IDIM);
    }
  };
  auto writeB = [&]() {
#pragma unroll
    for (int c = 0; c < 4; ++c) {
      u16x4 tg, tu;
#pragma unroll
      for (int i = 0; i < 4; ++i) { tg[i] = f2b(rg[i][c]); tu[i] = f2b(ru[i][c]); }
      const int wb = swzh(nq4 + c, kg4 * 2);
      *reinterpret_cast<u16x4*>(Bgs + wb) = tg;
      *reinterpret_cast<u16x4*>(Bus + wb) = tu;
    }
  };
  auto compute = [&](int abuf) {
#pragma unroll
    for (int ks = 0; ks < 2; ++ks) {
      const int kb = ks * 64 + fk * 16;
      bf16x8 a[4], bg[2], bu[2];
#pragma unroll
      for (int mi = 0; mi < 4; ++mi)
        a[mi] = *reinterpret_cast<const bf16x8*>(As + abuf + swzh(wm + mi * 16 + fr, kb));
#pragma unroll
      for (int ni = 0; ni < 2; ++ni) {
        bg[ni] = *reinterpret_cast<const bf16x8*>(Bgs + swzh(wn + ni * 16 + fr, kb));
        bu[ni] = *reinterpret_cast<const bf16x8*>(Bus + swzh(wn + ni * 16 + fr, kb));
      }
      __builtin_amdgcn_s_setprio(1);
#pragma unroll
      for (int mi = 0; mi < 4; ++mi)
#pragma unroll
        for (int ni = 0; ni < 2; ++ni) {
          accg[mi][ni] = __builtin_amdgcn_mfma_f32_16x16x32_bf16(a[mi], bg[ni], accg[mi][ni], 0, 0, 0);
          accu[mi][ni] = __builtin_amdgcn_mfma_f32_16x16x32_bf16(a[mi], bu[ni], accu[mi][ni], 0, 0, 0);
        }
      __builtin_amdgcn_s_setprio(0);
    }
  };

  stageA(0, 0);
  stageA(64, 16384);
  loadB(0);
  WAIT_VM0();
  writeB();
  WAIT_LGKM0();
  BARRIER();
  loadB(64);

  const int NT = HDIM / 64;  // 32
#pragma unroll 1
  for (int t = 0; t < NT; ++t) {
    compute((t & 1) * 16384);
    WAIT_LGKM0();
    BARRIER();
    if (t + 1 < NT) {
      WAIT_VM0();
      writeB();
    }
    if (t + 2 < NT) stageA((t + 2) * 64, (t & 1) * 16384);
    WAIT_LGKM0();
    BARRIER();
    if (t + 2 < NT) loadB((t + 2) * 64);
  }

#pragma unroll
  for (int mi = 0; mi < 4; ++mi)
#pragma unroll
    for (int ni = 0; ni < 2; ++ni)
#pragma unroll
      for (int r = 0; r < 4; ++r) {
        const int trow = wm + mi * 16 + fk * 4 + r;
        if (m0 + trow < cnt) {
          const int col = n0 + wn + ni * 16 + fr;
          const float g = accg[mi][ni][r];
          const float u = accu[mi][ni][r];
          const float a = (g / (1.f + __expf(-g))) * u * ws_s[trow];
          act[(size_t)slot_s[trow] * IDIM + col] = f2b(a);
        }
      }
}

// ---------------------------------------------------------------- GEMM2  (BM=128, BN=128, BK=64)
// out[token, :] {=, +=} act[slot, :] @ wd[e] — no atomics (twin-pass).
__global__ __launch_bounds__(256, 3) void gemm2_kernel(
    const unsigned short* __restrict__ act, const float* __restrict__ wd,
    const int* __restrict__ counts2, const int* __restrict__ list2,
    float* __restrict__ out, int add_mode) {
  const int bid = blockIdx.x;
  const int e = (bid & 7) + 8 * ((bid >> 3) & 1);
  const int rest = bid >> 4;               // 0..127
  const int mblk = rest & 7;
  const int nblk = rest >> 3;              // 0..15
  const int cnt = counts2[e];
  const int m0 = mblk * 128;
  if (m0 >= cnt) return;
  const int n0 = nblk * 128;

  __shared__ __align__(16) char As[2 * 128 * 128];  // 32 KB
  __shared__ __align__(16) char Bs[128 * 128];      // [128 n][64 k], 16 KB
  __shared__ int slot_s[128];

  const int tid = threadIdx.x;
  if (tid < 128) {
    int mr = m0 + tid;
    int mrc = mr < cnt ? mr : cnt - 1;
    slot_s[tid] = list2[e * TTOK + mrc];
  }
  __syncthreads();

  const int lane = tid & 63;
  const int wv = tid >> 6;

  const unsigned short* agsrc[4];
#pragma unroll
  for (int i = 0; i < 4; ++i) {
    const int r = i * 32 + wv * 8 + (lane >> 3);
    agsrc[i] = act + (size_t)slot_s[r] * IDIM + ((lane & 7) ^ rowhash(r)) * 8;
  }
  const int adst = wv * 8 * 128;

  const int nq4 = (tid & 31) * 4;          // n 0..127
  const int kg4 = (tid >> 5) * 4;          // k 0..31 (+32 for h=1)
  const float* bdp = wd + (size_t)e * (IDIM * HDIM) + (size_t)kg4 * HDIM + n0 + nq4;

  const int wm = (wv >> 1) * 64;
  const int wn = (wv & 1) * 64;
  const int fr = lane & 15;
  const int fk = lane >> 4;

  f32x4 acc[4][4];
#pragma unroll
  for (int mi = 0; mi < 4; ++mi)
#pragma unroll
    for (int ni = 0; ni < 4; ++ni) acc[mi][ni] = (f32x4){0.f, 0.f, 0.f, 0.f};

  f32x4 rb[2][4];
  auto stageA = [&](int kelem, int bufo) {
#pragma unroll
    for (int i = 0; i < 4; ++i)
      __builtin_amdgcn_global_load_lds(
          (const __attribute__((address_space(1))) unsigned int*)(agsrc[i] + kelem),
          (__attribute__((address_space(3))) unsigned int*)(As + bufo + adst + i * 4096),
          16, 0, 0);
  };
  auto loadB = [&](int k) {
#pragma unroll
    for (int h = 0; h < 2; ++h)
#pragma unroll
      for (int i = 0; i < 4; ++i)
        rb[h][i] = *reinterpret_cast<const f32x4*>(bdp + (size_t)(k + 32 * h + i) * HDIM);
  };
  auto writeB = [&]() {
#pragma unroll
    for (int h = 0; h < 2; ++h)
#pragma unroll
      for (int c = 0; c < 4; ++c) {
        u16x4 tb;
#pragma unroll
        for (int i = 0; i < 4; ++i) tb[i] = f2b(rb[h][i][c]);
        *reinterpret_cast<u16x4*>(Bs + swzh(nq4 + c, (kg4 + 32 * h) * 2)) = tb;
      }
  };
  auto compute = [&](int abuf) {
#pragma unroll
    for (int ks = 0; ks < 2; ++ks) {
      const int kb = ks * 64 + fk * 16;
      bf16x8 a[4], b[4];
#pragma unroll
      for (int mi = 0; mi < 4; ++mi)
        a[mi] = *reinterpret_cast<const bf16x8*>(As + abuf + swzh(wm + mi * 16 + fr, kb));
#pragma unroll
      for (int ni = 0; ni < 4; ++ni)
        b[ni] = *reinterpret_cast<const bf16x8*>(Bs + swzh(wn + ni * 16 + fr, kb));
      __builtin_amdgcn_s_setprio(1);
#pragma unroll
      for (int mi = 0; mi < 4; ++mi)
#pragma unroll
        for (int ni = 0; ni < 4; ++ni)
          acc[mi][ni] = __builtin_amdgcn_mfma_f32_16x16x32_bf16(a[mi], b[ni], acc[mi][ni], 0, 0, 0);
      __builtin_amdgcn_s_setprio(0);
    }
  };

  stageA(0, 0);
  stageA(64, 16384);
  loadB(0);
  WAIT_VM0();
  writeB();
  WAIT_LGKM0();
  BARRIER();
  loadB(64);

  const int NT = IDIM / 64;  // 16
#pragma unroll 1
  for (int t = 0; t < NT; ++t) {
    compute((t & 1) * 16384);
    WAIT_LGKM0();
    BARRIER();
    if (t + 1 < NT) {
      WAIT_VM0();
      writeB();
    }
    if (t + 2 < NT) stageA((t + 2) * 64, (t & 1) * 16384);
    WAIT_LGKM0();
    BARRIER();
    if (t + 2 < NT) loadB((t + 2) * 64);
  }

#pragma unroll
  for (int mi = 0; mi < 4; ++mi)
#pragma unroll
    for (int ni = 0; ni < 4; ++ni)
#pragma unroll
      for (int r = 0; r < 4; ++r) {
        const int trow = wm + mi * 16 + fk * 4 + r;
        if (m0 + trow < cnt) {
          const int tok = slot_s[trow] >> 1;
          const int col = n0 + wn + ni * 16 + fr;
          float* p = &out[(size_t)tok * HDIM + col];
          float v = acc[mi][ni][r];
          if (add_mode) v += *p;          // sole writer: plain RMW, no atomic
          *p = v;
        }
      }
}

// ---------------------------------------------------------------- launch
extern "C" void kernel_launch(void* const* d_in, const int* in_sizes, int n_in,
                              void* d_out, int out_size, void* d_ws, size_t ws_size,
                              hipStream_t stream) {
  const float* x = (const float*)d_in[0];
  const float* gate_w = (const float*)d_in[1];
  const float* wg = (const float*)d_in[2];
  const float* wu = (const float*)d_in[3];
  const float* wd = (const float*)d_in[4];
  float* out = (float*)d_out;

  char* w = (char*)d_ws;
  size_t off = 0;
  unsigned short* xb = (unsigned short*)(w + off); off += (size_t)TTOK * HDIM * 2;
  unsigned short* act = (unsigned short*)(w + off); off += (size_t)TTOK * KTOP * IDIM * 2;
  float* tw = (float*)(w + off); off += (size_t)TTOK * KTOP * 4;
  int* cnts = (int*)(w + off); off += 256;                     // [comb16 | prim16 | sec16]
  int* list  = (int*)(w + off); off += (size_t)NEXP * TTOK * 4;
  int* list0 = (int*)(w + off); off += (size_t)NEXP * TTOK * 4;
  int* list1 = (int*)(w + off); off += (size_t)NEXP * TTOK * 4;

  hipMemsetAsync(cnts, 0, 64, stream);   // only the combined counters
  gating_kernel<<<TTOK / 4, 256, 0, stream>>>(x, gate_w, xb, tw, cnts, list);
  split_kernel<<<NEXP, 256, 0, stream>>>(cnts, list, cnts + 16, list0, list1);
  // gemm1: 16 e x 8 m x 16 n = 2048 blocks (XCD-clustered decode in-kernel)
  gemm1_kernel<<<2048, 256, 0, stream>>>(xb, wg, wu, cnts, list, tw, act);
  // gemm2 pass A (primary slots): plain stores, covers every out element
  gemm2_kernel<<<2048, 256, 0, stream>>>(act, wd, cnts + 16, list0, out, 0);
  // gemm2 pass B (secondary slots): non-atomic read-add-store
  gemm2_kernel<<<2048, 256, 0, stream>>>(act, wd, cnts + 32, list1, out, 1);
}

// Round 14
// 317.690 us; speedup vs baseline: 2.8785x; 1.4699x over previous
//
#include <hip/hip_runtime.h>
#include <hip/hip_bf16.h>

#define HDIM 2048
#define IDIM 1024
#define NEXP 16
#define TTOK 4096   // B*S tokens
#define KTOP 2

typedef __attribute__((ext_vector_type(4))) float f32x4;
typedef __attribute__((ext_vector_type(8))) short bf16x8;
typedef __attribute__((ext_vector_type(4))) unsigned short u16x4;

__device__ __forceinline__ unsigned short f2b(float f) {
  __hip_bfloat16 h = __float2bfloat16(f);
  return *reinterpret_cast<unsigned short*>(&h);
}

// phase-boundary primitives
#define WAIT_VM0()   { asm volatile("s_waitcnt vmcnt(0)" ::: "memory"); __builtin_amdgcn_sched_barrier(0); }
#define WAIT_LGKM0() { asm volatile("s_waitcnt lgkmcnt(0)" ::: "memory"); __builtin_amdgcn_sched_barrier(0); }
#define BARRIER()    { __builtin_amdgcn_s_barrier(); __builtin_amdgcn_sched_barrier(0); }

// byte offset in a [rows][64 bf16] LDS tile (128 B/row), hash-swizzled.
__device__ __forceinline__ int swzh(int row, int kb) {
  return row * 128 + (kb ^ (((row ^ (row >> 3)) & 7) << 4));
}
__device__ __forceinline__ int rowhash(int r) { return (r ^ (r >> 3)) & 7; }

// ---------------------------------------------------------------- zero
__global__ __launch_bounds__(256) void zero_out_kernel(float* __restrict__ out) {
  const int n4 = TTOK * HDIM / 4;
  f32x4 z = {0.f, 0.f, 0.f, 0.f};
  for (int i = blockIdx.x * 256 + threadIdx.x; i < n4; i += gridDim.x * 256)
    reinterpret_cast<f32x4*>(out)[i] = z;
}

// ---------------------------------------------------------------- gating + x->bf16 (fused)
// NO global atomics: lane 0 writes weights + top-2 expert indices only.
// (16 shared counters in 2 cache lines serialized ~8192 device atomics —
//  that was ~75 us of pure contention.)
__global__ __launch_bounds__(256) void gating_kernel(const float* __restrict__ x,
                                                     const float* __restrict__ gw,
                                                     unsigned short* __restrict__ xb,
                                                     float* __restrict__ tw,
                                                     int2* __restrict__ tidx) {
  const int wv = threadIdx.x >> 6;
  const int lane = threadIdx.x & 63;
  const int t = blockIdx.x * 4 + wv;

  float acc[NEXP];
#pragma unroll
  for (int e = 0; e < NEXP; ++e) acc[e] = 0.f;

  const float* xr = x + (size_t)t * HDIM;
  unsigned short* xbr = xb + (size_t)t * HDIM;
#pragma unroll
  for (int j = 0; j < HDIM / 256; ++j) {
    f32x4 xv = *reinterpret_cast<const f32x4*>(xr + j * 256 + lane * 4);
    u16x4 o;
    o[0] = f2b(xv[0]); o[1] = f2b(xv[1]); o[2] = f2b(xv[2]); o[3] = f2b(xv[3]);
    *reinterpret_cast<u16x4*>(xbr + j * 256 + lane * 4) = o;
#pragma unroll
    for (int e = 0; e < NEXP; ++e) {
      f32x4 gv = *reinterpret_cast<const f32x4*>(gw + (size_t)e * HDIM + j * 256 + lane * 4);
      acc[e] = fmaf(xv[0], gv[0], acc[e]);
      acc[e] = fmaf(xv[1], gv[1], acc[e]);
      acc[e] = fmaf(xv[2], gv[2], acc[e]);
      acc[e] = fmaf(xv[3], gv[3], acc[e]);
    }
  }
#pragma unroll
  for (int e = 0; e < NEXP; ++e) {
#pragma unroll
    for (int off = 32; off; off >>= 1) acc[e] += __shfl_xor(acc[e], off);
  }
  // top-2 (ties -> lowest index, matching lax.top_k)
  int i0 = 0; float s0 = acc[0];
#pragma unroll
  for (int e = 1; e < NEXP; ++e) { if (acc[e] > s0) { s0 = acc[e]; i0 = e; } }
  int i1 = -1; float s1 = -1e30f;
#pragma unroll
  for (int e = 0; e < NEXP; ++e) { if (e != i0 && acc[e] > s1) { s1 = acc[e]; i1 = e; } }

  if (lane == 0) {
    float r = __expf(s1 - s0);          // <= 1
    float w0 = 1.f / (1.f + r);
    float w1 = r / (1.f + r);
    tw[t * 2 + 0] = w0;
    tw[t * 2 + 1] = w1;
    tidx[t] = make_int2(i0, i1);
  }
}

// ---------------------------------------------------------------- build lists
// One block; LDS-atomic cursors (16 banks — fast) build per-expert slot lists
// and final counts. Replaces 8192 contended device-scope atomics.
__global__ __launch_bounds__(1024) void build_lists_kernel(const int2* __restrict__ tidx,
                                                           int* __restrict__ counts,
                                                           int* __restrict__ list) {
  __shared__ int cur[NEXP];
  const int tid = threadIdx.x;
  if (tid < NEXP) cur[tid] = 0;
  __syncthreads();
  for (int t = tid; t < TTOK; t += 1024) {
    int2 ii = tidx[t];
    int p = atomicAdd(&cur[ii.x], 1);
    list[ii.x * TTOK + p] = t * 2;
    int q = atomicAdd(&cur[ii.y], 1);
    list[ii.y * TTOK + q] = t * 2 + 1;
  }
  __syncthreads();
  if (tid < NEXP) counts[tid] = cur[tid];
}

// ---------------------------------------------------------------- GEMM1  (BM=128, BN=64, BK=64)
// act[slot, :] = silu(x@wg) * (x@wu) * weight   (identical to passing R10)
__global__ __launch_bounds__(256, 3) void gemm1_kernel(
    const unsigned short* __restrict__ xb, const float* __restrict__ wg,
    const float* __restrict__ wu, const int* __restrict__ counts,
    const int* __restrict__ list, const float* __restrict__ tw,
    unsigned short* __restrict__ act) {
  const int bid = blockIdx.x;
  const int e = (bid & 7) + 8 * ((bid >> 3) & 1);
  const int rest = bid >> 4;               // 0..127
  const int mblk = rest & 7;
  const int nblk = rest >> 3;              // 0..15
  const int cnt = counts[e];
  const int m0 = mblk * 128;
  if (m0 >= cnt) return;
  const int n0 = nblk * 64;

  __shared__ __align__(16) char As[2 * 128 * 128];  // 2 x [128 m][64 k] bf16, 32 KB
  __shared__ __align__(16) char Bgs[64 * 128];      // [64 n][64 k] bf16, 8 KB
  __shared__ __align__(16) char Bus[64 * 128];
  __shared__ int slot_s[128];
  __shared__ float ws_s[128];

  const int tid = threadIdx.x;
  if (tid < 128) {
    int mr = m0 + tid;
    int mrc = mr < cnt ? mr : cnt - 1;
    int slot = list[e * TTOK + mrc];
    slot_s[tid] = slot;
    ws_s[tid] = tw[slot];
  }
  __syncthreads();

  const int lane = tid & 63;
  const int wv = tid >> 6;

  const unsigned short* agsrc[4];
#pragma unroll
  for (int i = 0; i < 4; ++i) {
    const int r = i * 32 + wv * 8 + (lane >> 3);
    agsrc[i] = xb + (size_t)(slot_s[r] >> 1) * HDIM + ((lane & 7) ^ rowhash(r)) * 8;
  }
  const int adst = wv * 8 * 128;

  const int nq4 = (tid & 15) * 4;
  const int kg4 = (tid >> 4) * 4;
  const float* bgp = wg + (size_t)e * (HDIM * IDIM) + (size_t)kg4 * IDIM + n0 + nq4;
  const float* bup = wu + (size_t)e * (HDIM * IDIM) + (size_t)kg4 * IDIM + n0 + nq4;

  const int wm = (wv >> 1) * 64;
  const int wn = (wv & 1) * 32;
  const int fr = lane & 15;
  const int fk = lane >> 4;

  f32x4 accg[4][2], accu[4][2];
#pragma unroll
  for (int mi = 0; mi < 4; ++mi)
#pragma unroll
    for (int ni = 0; ni < 2; ++ni) {
      accg[mi][ni] = (f32x4){0.f, 0.f, 0.f, 0.f};
      accu[mi][ni] = (f32x4){0.f, 0.f, 0.f, 0.f};
    }

  f32x4 rg[4], ru[4];
  auto stageA = [&](int kelem, int bufo) {
#pragma unroll
    for (int i = 0; i < 4; ++i)
      __builtin_amdgcn_global_load_lds(
          (const __attribute__((address_space(1))) unsigned int*)(agsrc[i] + kelem),
          (__attribute__((address_space(3))) unsigned int*)(As + bufo + adst + i * 4096),
          16, 0, 0);
  };
  auto loadB = [&](int k) {
#pragma unroll
    for (int i = 0; i < 4; ++i) {
      rg[i] = *reinterpret_cast<const f32x4*>(bgp + (size_t)(k + i) * IDIM);
      ru[i] = *reinterpret_cast<const f32x4*>(bup + (size_t)(k + i) * IDIM);
    }
  };
  auto writeB = [&]() {
#pragma unroll
    for (int c = 0; c < 4; ++c) {
      u16x4 tg, tu;
#pragma unroll
      for (int i = 0; i < 4; ++i) { tg[i] = f2b(rg[i][c]); tu[i] = f2b(ru[i][c]); }
      const int wb = swzh(nq4 + c, kg4 * 2);
      *reinterpret_cast<u16x4*>(Bgs + wb) = tg;
      *reinterpret_cast<u16x4*>(Bus + wb) = tu;
    }
  };
  auto compute = [&](int abuf) {
#pragma unroll
    for (int ks = 0; ks < 2; ++ks) {
      const int kb = ks * 64 + fk * 16;
      bf16x8 a[4], bg[2], bu[2];
#pragma unroll
      for (int mi = 0; mi < 4; ++mi)
        a[mi] = *reinterpret_cast<const bf16x8*>(As + abuf + swzh(wm + mi * 16 + fr, kb));
#pragma unroll
      for (int ni = 0; ni < 2; ++ni) {
        bg[ni] = *reinterpret_cast<const bf16x8*>(Bgs + swzh(wn + ni * 16 + fr, kb));
        bu[ni] = *reinterpret_cast<const bf16x8*>(Bus + swzh(wn + ni * 16 + fr, kb));
      }
      __builtin_amdgcn_s_setprio(1);
#pragma unroll
      for (int mi = 0; mi < 4; ++mi)
#pragma unroll
        for (int ni = 0; ni < 2; ++ni) {
          accg[mi][ni] = __builtin_amdgcn_mfma_f32_16x16x32_bf16(a[mi], bg[ni], accg[mi][ni], 0, 0, 0);
          accu[mi][ni] = __builtin_amdgcn_mfma_f32_16x16x32_bf16(a[mi], bu[ni], accu[mi][ni], 0, 0, 0);
        }
      __builtin_amdgcn_s_setprio(0);
    }
  };

  stageA(0, 0);
  stageA(64, 16384);
  loadB(0);
  WAIT_VM0();
  writeB();
  WAIT_LGKM0();
  BARRIER();
  loadB(64);

  const int NT = HDIM / 64;  // 32
#pragma unroll 1
  for (int t = 0; t < NT; ++t) {
    compute((t & 1) * 16384);
    WAIT_LGKM0();
    BARRIER();
    if (t + 1 < NT) {
      WAIT_VM0();
      writeB();
    }
    if (t + 2 < NT) stageA((t + 2) * 64, (t & 1) * 16384);
    WAIT_LGKM0();
    BARRIER();
    if (t + 2 < NT) loadB((t + 2) * 64);
  }

#pragma unroll
  for (int mi = 0; mi < 4; ++mi)
#pragma unroll
    for (int ni = 0; ni < 2; ++ni)
#pragma unroll
      for (int r = 0; r < 4; ++r) {
        const int trow = wm + mi * 16 + fk * 4 + r;
        if (m0 + trow < cnt) {
          const int col = n0 + wn + ni * 16 + fr;
          const float g = accg[mi][ni][r];
          const float u = accu[mi][ni][r];
          const float a = (g / (1.f + __expf(-g))) * u * ws_s[trow];
          act[(size_t)slot_s[trow] * IDIM + col] = f2b(a);
        }
      }
}

// ---------------------------------------------------------------- GEMM2  (BM=128, BN=128, BK=64)
// out[token, :] += act[slot, :] @ wd[e]  (identical to passing R10; atomics
// on distinct addresses — contention-free)
__global__ __launch_bounds__(256, 3) void gemm2_kernel(
    const unsigned short* __restrict__ act, const float* __restrict__ wd,
    const int* __restrict__ counts, const int* __restrict__ list,
    float* __restrict__ out) {
  const int bid = blockIdx.x;
  const int e = (bid & 7) + 8 * ((bid >> 3) & 1);
  const int rest = bid >> 4;               // 0..127
  const int mblk = rest & 7;
  const int nblk = rest >> 3;              // 0..15
  const int cnt = counts[e];
  const int m0 = mblk * 128;
  if (m0 >= cnt) return;
  const int n0 = nblk * 128;

  __shared__ __align__(16) char As[2 * 128 * 128];  // 32 KB
  __shared__ __align__(16) char Bs[128 * 128];      // [128 n][64 k], 16 KB
  __shared__ int slot_s[128];

  const int tid = threadIdx.x;
  if (tid < 128) {
    int mr = m0 + tid;
    int mrc = mr < cnt ? mr : cnt - 1;
    slot_s[tid] = list[e * TTOK + mrc];
  }
  __syncthreads();

  const int lane = tid & 63;
  const int wv = tid >> 6;

  const unsigned short* agsrc[4];
#pragma unroll
  for (int i = 0; i < 4; ++i) {
    const int r = i * 32 + wv * 8 + (lane >> 3);
    agsrc[i] = act + (size_t)slot_s[r] * IDIM + ((lane & 7) ^ rowhash(r)) * 8;
  }
  const int adst = wv * 8 * 128;

  const int nq4 = (tid & 31) * 4;          // n 0..127
  const int kg4 = (tid >> 5) * 4;          // k 0..31 (+32 for h=1)
  const float* bdp = wd + (size_t)e * (IDIM * HDIM) + (size_t)kg4 * HDIM + n0 + nq4;

  const int wm = (wv >> 1) * 64;
  const int wn = (wv & 1) * 64;
  const int fr = lane & 15;
  const int fk = lane >> 4;

  f32x4 acc[4][4];
#pragma unroll
  for (int mi = 0; mi < 4; ++mi)
#pragma unroll
    for (int ni = 0; ni < 4; ++ni) acc[mi][ni] = (f32x4){0.f, 0.f, 0.f, 0.f};

  f32x4 rb[2][4];
  auto stageA = [&](int kelem, int bufo) {
#pragma unroll
    for (int i = 0; i < 4; ++i)
      __builtin_amdgcn_global_load_lds(
          (const __attribute__((address_space(1))) unsigned int*)(agsrc[i] + kelem),
          (__attribute__((address_space(3))) unsigned int*)(As + bufo + adst + i * 4096),
          16, 0, 0);
  };
  auto loadB = [&](int k) {
#pragma unroll
    for (int h = 0; h < 2; ++h)
#pragma unroll
      for (int i = 0; i < 4; ++i)
        rb[h][i] = *reinterpret_cast<const f32x4*>(bdp + (size_t)(k + 32 * h + i) * HDIM);
  };
  auto writeB = [&]() {
#pragma unroll
    for (int h = 0; h < 2; ++h)
#pragma unroll
      for (int c = 0; c < 4; ++c) {
        u16x4 tb;
#pragma unroll
        for (int i = 0; i < 4; ++i) tb[i] = f2b(rb[h][i][c]);
        *reinterpret_cast<u16x4*>(Bs + swzh(nq4 + c, (kg4 + 32 * h) * 2)) = tb;
      }
  };
  auto compute = [&](int abuf) {
#pragma unroll
    for (int ks = 0; ks < 2; ++ks) {
      const int kb = ks * 64 + fk * 16;
      bf16x8 a[4], b[4];
#pragma unroll
      for (int mi = 0; mi < 4; ++mi)
        a[mi] = *reinterpret_cast<const bf16x8*>(As + abuf + swzh(wm + mi * 16 + fr, kb));
#pragma unroll
      for (int ni = 0; ni < 4; ++ni)
        b[ni] = *reinterpret_cast<const bf16x8*>(Bs + swzh(wn + ni * 16 + fr, kb));
      __builtin_amdgcn_s_setprio(1);
#pragma unroll
      for (int mi = 0; mi < 4; ++mi)
#pragma unroll
        for (int ni = 0; ni < 4; ++ni)
          acc[mi][ni] = __builtin_amdgcn_mfma_f32_16x16x32_bf16(a[mi], b[ni], acc[mi][ni], 0, 0, 0);
      __builtin_amdgcn_s_setprio(0);
    }
  };

  stageA(0, 0);
  stageA(64, 16384);
  loadB(0);
  WAIT_VM0();
  writeB();
  WAIT_LGKM0();
  BARRIER();
  loadB(64);

  const int NT = IDIM / 64;  // 16
#pragma unroll 1
  for (int t = 0; t < NT; ++t) {
    compute((t & 1) * 16384);
    WAIT_LGKM0();
    BARRIER();
    if (t + 1 < NT) {
      WAIT_VM0();
      writeB();
    }
    if (t + 2 < NT) stageA((t + 2) * 64, (t & 1) * 16384);
    WAIT_LGKM0();
    BARRIER();
    if (t + 2 < NT) loadB((t + 2) * 64);
  }

#pragma unroll
  for (int mi = 0; mi < 4; ++mi)
#pragma unroll
    for (int ni = 0; ni < 4; ++ni)
#pragma unroll
      for (int r = 0; r < 4; ++r) {
        const int trow = wm + mi * 16 + fk * 4 + r;
        if (m0 + trow < cnt) {
          const int t = slot_s[trow] >> 1;
          const int col = n0 + wn + ni * 16 + fr;
          atomicAdd(&out[(size_t)t * HDIM + col], acc[mi][ni][r]);
        }
      }
}

// ---------------------------------------------------------------- launch
extern "C" void kernel_launch(void* const* d_in, const int* in_sizes, int n_in,
                              void* d_out, int out_size, void* d_ws, size_t ws_size,
                              hipStream_t stream) {
  const float* x = (const float*)d_in[0];
  const float* gate_w = (const float*)d_in[1];
  const float* wg = (const float*)d_in[2];
  const float* wu = (const float*)d_in[3];
  const float* wd = (const float*)d_in[4];
  float* out = (float*)d_out;

  char* w = (char*)d_ws;
  size_t off = 0;
  unsigned short* xb = (unsigned short*)(w + off); off += (size_t)TTOK * HDIM * 2;
  unsigned short* act = (unsigned short*)(w + off); off += (size_t)TTOK * KTOP * IDIM * 2;
  float* tw = (float*)(w + off); off += (size_t)TTOK * KTOP * 4;
  int2* tidx = (int2*)(w + off); off += (size_t)TTOK * 8;
  int* counts = (int*)(w + off); off += 256;
  int* list = (int*)(w + off); off += (size_t)NEXP * TTOK * 4;

  zero_out_kernel<<<2048, 256, 0, stream>>>(out);
  gating_kernel<<<TTOK / 4, 256, 0, stream>>>(x, gate_w, xb, tw, tidx);
  build_lists_kernel<<<1, 1024, 0, stream>>>(tidx, counts, list);
  // gemm1: 16 e x 8 m x 16 n = 2048 blocks (XCD-clustered decode in-kernel)
  gemm1_kernel<<<2048, 256, 0, stream>>>(xb, wg, wu, counts, list, tw, act);
  // gemm2: 16 e x 8 m x 16 n = 2048 blocks
  gemm2_kernel<<<2048, 256, 0, stream>>>(act, wd, counts, list, out);
}